// Round 3
// baseline (716.686 us; speedup 1.0000x reference)
//
#include <hip/hip_runtime.h>
#include <hip/hip_cooperative_groups.h>
#include <stdint.h>

namespace cg = cooperative_groups;

#define B_     64
#define H_     16384
#define NB_    512
#define NNZ_   26214
#define N_IN_  1024
#define N_OUT_ 1024

typedef __attribute__((ext_vector_type(8))) short    bf16x8;
typedef __attribute__((ext_vector_type(4))) float    f32x4;
typedef __attribute__((ext_vector_type(4))) unsigned int u32x4;

__device__ __forceinline__ unsigned short f2bf(float f) {
    union { unsigned int i; float f; } v; v.f = f;
    unsigned int x = v.i;
    return (unsigned short)((x + 0x7fffu + ((x >> 16) & 1u)) >> 16);
}

__device__ __forceinline__ bf16x8 ldfrag(const unsigned short* p) {
    union { u32x4 u; bf16x8 b; } cv;
    cv.u = *(const u32x4*)p;     // 16B aligned by construction
    return cv.b;
}

// ---------------- index build (tiny, graph-safe, redone every call) ---------

__global__ void zero_cnt(int* __restrict__ cnt) { cnt[threadIdx.x] = 0; }

__global__ void hist(const int* __restrict__ rows, int* __restrict__ cnt) {
    int n = blockIdx.x * 256 + threadIdx.x;
    if (n < NNZ_) atomicAdd(&cnt[rows[n]], 1);
}

__global__ void scan_k(int* __restrict__ cnt, int* __restrict__ ptr) {
    __shared__ int tmp[NB_];
    int t = threadIdx.x;
    tmp[t] = cnt[t];
    __syncthreads();
    for (int off = 1; off < NB_; off <<= 1) {
        int v = (t >= off) ? tmp[t - off] : 0;
        __syncthreads();
        tmp[t] += v;
        __syncthreads();
    }
    if (t == 0) ptr[0] = 0;
    ptr[t + 1] = tmp[t];
    cnt[t] = 0;
}

// writes packed (n, col) pairs sorted by row
__global__ void scatter2(const int* __restrict__ rows, const int* __restrict__ cols,
                         const int* __restrict__ ptr, int* __restrict__ cnt,
                         int2* __restrict__ pair2) {
    int n = blockIdx.x * 256 + threadIdx.x;
    if (n < NNZ_) {
        int r = rows[n];
        int pos = ptr[r] + atomicAdd(&cnt[r], 1);
        pair2[pos] = make_int2(n, cols[n]);
    }
}

// ---------------- weights f32 -> bf16 (RNE), PERMUTED to row-sorted order ---

__global__ __launch_bounds__(256) void conv_w(const float* __restrict__ w,
                                              unsigned short* __restrict__ wb,
                                              const int2* __restrict__ pair2) {
    int pos = blockIdx.x;
    int t   = threadIdx.x;                 // one float4 per thread, 256 = 1024 floats
    int n   = pair2[pos].x;
    f32x4 v = __builtin_nontemporal_load((const f32x4*)(w + (size_t)n * 1024) + t);
    union { unsigned short s[4]; uint2 d; } o;
    o.s[0] = f2bf(v[0]); o.s[1] = f2bf(v[1]); o.s[2] = f2bf(v[2]); o.s[3] = f2bf(v[3]);
    ((uint2*)(wb + (size_t)pos * 1024))[t] = o.d;
}

// ---------------- init: blocked x[c][b][j] bf16 from inp (zero-padded) ------

__global__ __launch_bounds__(256) void init_x(const float* __restrict__ inp,
                                              unsigned short* __restrict__ xb) {
    int idx = blockIdx.x * 256 + threadIdx.x;   // 0 .. B*H-1 (blocked linear)
    int c = idx >> 11;          // 64*32 = 2048 elements per c-slab
    int b = (idx >> 5) & 63;
    int j = idx & 31;
    int h = c * 32 + j;
    xb[idx] = (h < N_IN_) ? f2bf(inp[b * N_IN_ + h]) : (unsigned short)0;
}

// ---------------- shared step machinery -------------------------------------
// LDS: s_pairs 4KB + s_red[4][64][33] 33.8KB = 37.9KB (<64KB: cooperative
// occupancy validation passes; 2 WG/CU with __launch_bounds__(512,4)).
// 8-wave reduce done in two phases: waves 4..7 dump, waves 0..3 add in place,
// epilogue sums 4 slices.

#define MFMA8(A, Bv)                                                         \
    do {                                                                     \
        _Pragma("unroll")                                                    \
        for (int mt = 0; mt < 2; ++mt)                                       \
            _Pragma("unroll")                                                \
            for (int nt = 0; nt < 4; ++nt)                                   \
                acc[mt][nt] = __builtin_amdgcn_mfma_f32_16x16x32_bf16(       \
                                  A[mt], Bv[nt], acc[mt][nt], 0, 0, 0);      \
    } while (0)

#define LDFRAGS(A, Bv, p)                                                    \
    do {                                                                     \
        const unsigned short* wp =                                           \
            wb + (size_t)(p).x * 1024 + half * 32 + quad * 8;                \
        A[0] = ldfrag(wp);                                                   \
        A[1] = ldfrag(wp + 16 * 32);                                         \
        const unsigned short* xp =                                           \
            x + ((size_t)(p).y * 64 + half) * 32 + quad * 8;                 \
        Bv[0] = ldfrag(xp);                                                  \
        Bv[1] = ldfrag(xp + 16 * 32);                                        \
        Bv[2] = ldfrag(xp + 32 * 32);                                        \
        Bv[3] = ldfrag(xp + 48 * 32);                                        \
    } while (0)

// ---------------- ALL 8 steps in one persistent cooperative kernel ----------

__global__ __launch_bounds__(512, 4) void fused_k(
        const unsigned short* __restrict__ xa,   // [NB][64][32] bf16 (step-even src)
        unsigned short* __restrict__ xb_,        // [NB][64][32] bf16 (step-even dst)
        float* __restrict__ out,                 // [B][N_OUT] f32
        const unsigned short* __restrict__ wb,   // [NNZ][32][32] bf16, permuted
        const float* __restrict__ bias,
        const int2* __restrict__ pair2,          // row-sorted (n, c); .x == wbf idx
        const int* __restrict__ ptr) {
    __shared__ int2  s_pairs[8][64];             // 4 KB
    __shared__ float s_red[4][64][33];           // 33.8 KB

    const int r    = blockIdx.x;
    const int tid  = threadIdx.x;
    const int wv   = tid >> 6;                   // 0..7
    const int lane = tid & 63;
    const int half = lane & 15;
    const int quad = lane >> 4;

    const int beg = ptr[r], cnt = ptr[r + 1] - beg;
    const int c0 = beg + (cnt * wv) / 8;
    const int m  = beg + (cnt * (wv + 1)) / 8 - c0;

    // fetch this wave's pairs ONCE; reused every step
    int2 pcl = make_int2(0, 0);
    const bool have = (lane < m);
    if (have) pcl = make_int2(c0 + lane, pair2[c0 + lane].y);

    // epilogue constants (same every step)
    const int b  = tid >> 3;
    const int i0 = (tid & 7) * 4;
    const float4 bv = *(const float4*)&bias[r * 32 + i0];

    cg::grid_group grid = cg::this_grid();

    for (int step = 0; step < 8; ++step) {
        const bool last = (step == 7);
        if (!last || r >= NB_ - N_OUT_ / 32) {
            const unsigned short* x  = (step & 1) ? xb_ : xa;
            unsigned short*       xo = (step & 1) ? const_cast<unsigned short*>(xa) : xb_;
            const int col_limit = (step == 0) ? (N_IN_ / 32) : NB_;

            // ballot-compaction of this wave's pairs under col_limit
            bool valid = have && (pcl.y < col_limit);
            unsigned long long mask = __ballot(valid);
            if (valid) {
                int pos = __popcll(mask & ((1ull << lane) - 1ull));
                s_pairs[wv][pos] = pcl;          // intra-wave only: no barrier
            }
            const int mv = __popcll(mask);

            f32x4 acc[2][4] = {};
            bf16x8 A0[2], B0[4], A1[2], B1[4];

            if (mv > 0) { int2 p = s_pairs[wv][0]; LDFRAGS(A0, B0, p); }
            int j = 0;
            while (j + 2 <= mv) {
                { int2 p = s_pairs[wv][j + 1]; LDFRAGS(A1, B1, p); }
                MFMA8(A0, B0);
                if (j + 2 < mv) { int2 p = s_pairs[wv][j + 2]; LDFRAGS(A0, B0, p); }
                MFMA8(A1, B1);
                j += 2;
            }
            if (j < mv) MFMA8(A0, B0);

            // two-phase reduce. C/D layout: col(b)=lane&15, row(i)=quad*4+q
            if (wv >= 4) {
                #pragma unroll
                for (int mt = 0; mt < 2; ++mt)
                    #pragma unroll
                    for (int nt = 0; nt < 4; ++nt)
                        #pragma unroll
                        for (int q2 = 0; q2 < 4; ++q2)
                            s_red[wv - 4][nt * 16 + half][mt * 16 + quad * 4 + q2] =
                                acc[mt][nt][q2];
            }
            __syncthreads();
            if (wv < 4) {
                #pragma unroll
                for (int mt = 0; mt < 2; ++mt)
                    #pragma unroll
                    for (int nt = 0; nt < 4; ++nt)
                        #pragma unroll
                        for (int q2 = 0; q2 < 4; ++q2)
                            s_red[wv][nt * 16 + half][mt * 16 + quad * 4 + q2] +=
                                acc[mt][nt][q2];
            }
            __syncthreads();

            // 4-slice reduce + bias + activation + store
            float v[4] = {bv.x, bv.y, bv.z, bv.w};
            #pragma unroll
            for (int w = 0; w < 4; ++w)
                #pragma unroll
                for (int k = 0; k < 4; ++k)
                    v[k] += s_red[w][b][i0 + k];
            if (last) {
                float4 o;
                o.x = 1.0f / (1.0f + __expf(-v[0]));
                o.y = 1.0f / (1.0f + __expf(-v[1]));
                o.z = 1.0f / (1.0f + __expf(-v[2]));
                o.w = 1.0f / (1.0f + __expf(-v[3]));
                *(float4*)&out[(size_t)b * N_OUT_ +
                               (r - (NB_ - N_OUT_ / 32)) * 32 + i0] = o;
            } else {
                union { unsigned short s[4]; uint2 u; } o;
                #pragma unroll
                for (int k = 0; k < 4; ++k)
                    o.s[k] = f2bf(1.0f / (1.0f + __expf(-v[k])));
                *(uint2*)&xo[((size_t)r * 64 + b) * 32 + i0] = o.u;
            }
        }
        if (step < 7) grid.sync();   // xout fully written before next step reads
    }
}

// ---------------- fallback: one step per launch (round-0 proven path) -------

template <bool LAST>
__global__ __launch_bounds__(512, 4) void rowstep_k(
        const unsigned short* __restrict__ x,
        unsigned short* __restrict__ xout,
        float* __restrict__ out,
        const unsigned short* __restrict__ wb,   // permuted order
        const float* __restrict__ bias,
        const int2* __restrict__ pair2,
        const int* __restrict__ ptr,
        int row_base, int col_limit) {
    __shared__ int2  s_pairs[8][64];
    __shared__ float s_red[4][64][33];

    const int r    = blockIdx.x + row_base;
    const int tid  = threadIdx.x;
    const int wv   = tid >> 6;
    const int lane = tid & 63;
    const int half = lane & 15;
    const int quad = lane >> 4;

    const int beg = ptr[r], cnt = ptr[r + 1] - beg;
    const int c0 = beg + (cnt * wv) / 8;
    const int m  = beg + (cnt * (wv + 1)) / 8 - c0;

    int2 pc = make_int2(0, 0);
    bool valid = (lane < m);
    if (valid) {
        int c = pair2[c0 + lane].y;
        pc = make_int2(c0 + lane, c);
        valid = (c < col_limit);
    }
    unsigned long long mask = __ballot(valid);
    if (valid) {
        int pos = __popcll(mask & ((1ull << lane) - 1ull));
        s_pairs[wv][pos] = pc;
    }
    const int mv = __popcll(mask);

    f32x4 acc[2][4] = {};
    bf16x8 A0[2], B0[4], A1[2], B1[4];

    if (mv > 0) { int2 p = s_pairs[wv][0]; LDFRAGS(A0, B0, p); }
    int j = 0;
    while (j + 2 <= mv) {
        { int2 p = s_pairs[wv][j + 1]; LDFRAGS(A1, B1, p); }
        MFMA8(A0, B0);
        if (j + 2 < mv) { int2 p = s_pairs[wv][j + 2]; LDFRAGS(A0, B0, p); }
        MFMA8(A1, B1);
        j += 2;
    }
    if (j < mv) MFMA8(A0, B0);

    if (wv >= 4) {
        #pragma unroll
        for (int mt = 0; mt < 2; ++mt)
            #pragma unroll
            for (int nt = 0; nt < 4; ++nt)
                #pragma unroll
                for (int q2 = 0; q2 < 4; ++q2)
                    s_red[wv - 4][nt * 16 + half][mt * 16 + quad * 4 + q2] =
                        acc[mt][nt][q2];
    }
    __syncthreads();
    if (wv < 4) {
        #pragma unroll
        for (int mt = 0; mt < 2; ++mt)
            #pragma unroll
            for (int nt = 0; nt < 4; ++nt)
                #pragma unroll
                for (int q2 = 0; q2 < 4; ++q2)
                    s_red[wv][nt * 16 + half][mt * 16 + quad * 4 + q2] +=
                        acc[mt][nt][q2];
    }
    __syncthreads();

    const int b  = tid >> 3;
    const int i0 = (tid & 7) * 4;
    const float4 bv = *(const float4*)&bias[r * 32 + i0];
    float v[4] = {bv.x, bv.y, bv.z, bv.w};
    #pragma unroll
    for (int w = 0; w < 4; ++w)
        #pragma unroll
        for (int k = 0; k < 4; ++k)
            v[k] += s_red[w][b][i0 + k];
    if (LAST) {
        float4 o;
        o.x = 1.0f / (1.0f + __expf(-v[0]));
        o.y = 1.0f / (1.0f + __expf(-v[1]));
        o.z = 1.0f / (1.0f + __expf(-v[2]));
        o.w = 1.0f / (1.0f + __expf(-v[3]));
        *(float4*)&out[(size_t)b * N_OUT_ + (r - (NB_ - N_OUT_ / 32)) * 32 + i0] = o;
    } else {
        union { unsigned short s[4]; uint2 u; } o;
        #pragma unroll
        for (int k = 0; k < 4; ++k)
            o.s[k] = f2bf(1.0f / (1.0f + __expf(-v[k])));
        *(uint2*)&xout[((size_t)r * 64 + b) * 32 + i0] = o.u;
    }
}

// ---------------- launcher --------------------------------------------------

extern "C" void kernel_launch(void* const* d_in, const int* in_sizes, int n_in,
                              void* d_out, int out_size, void* d_ws, size_t ws_size,
                              hipStream_t stream) {
    const float* inp    = (const float*)d_in[0];
    const float* blocks = (const float*)d_in[1];
    const float* bias   = (const float*)d_in[2];
    const int*   rows   = (const int*)d_in[3];
    const int*   cols   = (const int*)d_in[4];
    float*       out    = (float*)d_out;

    char* ws = (char*)d_ws;
    unsigned short* wbf = (unsigned short*)ws;                       // 53.69 MB
    unsigned short* x0  = (unsigned short*)(ws + 53686272u);         // 2 MB
    unsigned short* x1  = (unsigned short*)(ws + 53686272u + 2097152u);
    char*  idxbase      = ws + 53686272u + 2u * 2097152u;
    int*   rowptr = (int*)(idxbase);                                  // 513 ints
    int*   rowcnt = (int*)(idxbase + 4096);                           // 512 ints
    int2*  pair2  = (int2*)(idxbase + 8192);                          // NNZ int2

    // index build (must precede conv_w: permutation comes from pair2)
    zero_cnt<<<1, NB_, 0, stream>>>(rowcnt);
    hist<<<(NNZ_ + 255) / 256, 256, 0, stream>>>(rows, rowcnt);
    scan_k<<<1, NB_, 0, stream>>>(rowcnt, rowptr);
    scatter2<<<(NNZ_ + 255) / 256, 256, 0, stream>>>(rows, cols, rowptr, rowcnt, pair2);

    // weights -> bf16, permuted into row-sorted (pair) order
    conv_w<<<NNZ_, 256, 0, stream>>>(blocks, wbf, pair2);

    init_x<<<(B_ * H_) / 256, 256, 0, stream>>>(inp, x0);

    // all 8 steps, one persistent cooperative dispatch (512 WGs = 2/CU resident)
    void* kargs[] = { (void*)&x0, (void*)&x1, (void*)&out, (void*)&wbf,
                      (void*)&bias, (void*)&pair2, (void*)&rowptr };
    hipError_t ce = hipLaunchCooperativeKernel(
        reinterpret_cast<void*>(fused_k), dim3(NB_), dim3(512), kargs, 0, stream);

    if (ce != hipSuccess) {
        (void)hipGetLastError();   // clear sticky error; fall back to 8 launches
        unsigned short* cur = x0;
        unsigned short* nxt = x1;
        rowstep_k<false><<<NB_, 512, 0, stream>>>(cur, nxt, nullptr, wbf, bias,
                                                  pair2, rowptr, 0, 32);
        { unsigned short* t = cur; cur = nxt; nxt = t; }
        for (int s = 1; s < 7; ++s) {
            rowstep_k<false><<<NB_, 512, 0, stream>>>(cur, nxt, nullptr, wbf, bias,
                                                      pair2, rowptr, 0, NB_);
            unsigned short* t = cur; cur = nxt; nxt = t;
        }
        rowstep_k<true><<<N_OUT_ / 32, 512, 0, stream>>>(cur, nullptr, out, wbf, bias,
                                                         pair2, rowptr,
                                                         NB_ - N_OUT_ / 32, NB_);
    }
}

// Round 5
// 311.414 us; speedup vs baseline: 2.3014x; 2.3014x over previous
//
#include <hip/hip_runtime.h>
#include <stdint.h>

#define B_     64
#define H_     16384
#define NB_    512
#define NNZ_   26214
#define N_IN_  1024
#define N_OUT_ 1024

typedef __attribute__((ext_vector_type(8))) short    bf16x8;
typedef __attribute__((ext_vector_type(4))) float    f32x4;
typedef __attribute__((ext_vector_type(4))) unsigned int u32x4;

__device__ __forceinline__ unsigned short f2bf(float f) {
    union { unsigned int i; float f; } v; v.f = f;
    unsigned int x = v.i;
    return (unsigned short)((x + 0x7fffu + ((x >> 16) & 1u)) >> 16);
}

__device__ __forceinline__ bf16x8 ldfrag(const unsigned short* p) {
    union { u32x4 u; bf16x8 b; } cv;
    cv.u = *(const u32x4*)p;     // 16B aligned by construction
    return cv.b;
}

// ---------------- index build (tiny, graph-safe, redone every call) ---------

__global__ void zero_cnt(int* __restrict__ cnt) { cnt[threadIdx.x] = 0; }

__global__ void hist(const int* __restrict__ rows, int* __restrict__ cnt) {
    int n = blockIdx.x * 256 + threadIdx.x;
    if (n < NNZ_) atomicAdd(&cnt[rows[n]], 1);
}

__global__ void scan_k(int* __restrict__ cnt, int* __restrict__ ptr) {
    __shared__ int tmp[NB_];
    int t = threadIdx.x;
    tmp[t] = cnt[t];
    __syncthreads();
    for (int off = 1; off < NB_; off <<= 1) {
        int v = (t >= off) ? tmp[t - off] : 0;
        __syncthreads();
        tmp[t] += v;
        __syncthreads();
    }
    if (t == 0) ptr[0] = 0;
    ptr[t + 1] = tmp[t];
    cnt[t] = 0;
}

// writes packed (n, col) pairs sorted by row
__global__ void scatter2(const int* __restrict__ rows, const int* __restrict__ cols,
                         const int* __restrict__ ptr, int* __restrict__ cnt,
                         int2* __restrict__ pair2) {
    int n = blockIdx.x * 256 + threadIdx.x;
    if (n < NNZ_) {
        int r = rows[n];
        int pos = ptr[r] + atomicAdd(&cnt[r], 1);
        pair2[pos] = make_int2(n, cols[n]);
    }
}

// ---------------- weights f32 -> bf16 (RNE), PERMUTED to row-sorted order ---
// wbf[pos] = bf16(blocks[pair2[pos].x]) -> weight address for pair j of a
// wave's range is base + j*2KB: pure stride, no indirection in the hot loop.

__global__ __launch_bounds__(256) void conv_w(const float* __restrict__ w,
                                              unsigned short* __restrict__ wb,
                                              const int2* __restrict__ pair2) {
    int pos = blockIdx.x;
    int t   = threadIdx.x;                 // one float4 per thread, 256 = 1024 floats
    int n   = pair2[pos].x;
    f32x4 v = __builtin_nontemporal_load((const f32x4*)(w + (size_t)n * 1024) + t);
    union { unsigned short s[4]; uint2 d; } o;
    o.s[0] = f2bf(v[0]); o.s[1] = f2bf(v[1]); o.s[2] = f2bf(v[2]); o.s[3] = f2bf(v[3]);
    ((uint2*)(wb + (size_t)pos * 1024))[t] = o.d;
}

// ---------------- init: blocked x[c][b][j] bf16 from inp (zero-padded) ------

__global__ __launch_bounds__(256) void init_x(const float* __restrict__ inp,
                                              unsigned short* __restrict__ xb) {
    int idx = blockIdx.x * 256 + threadIdx.x;   // 0 .. B*H-1 (blocked linear)
    int c = idx >> 11;          // 64*32 = 2048 elements per c-slab
    int b = (idx >> 5) & 63;
    int j = idx & 31;
    int h = c * 32 + j;
    xb[idx] = (h < N_IN_) ? f2bf(inp[b * N_IN_ + h]) : (unsigned short)0;
}

// ---------------- common pieces ---------------------------------------------

#define MFMA8(A, Bv)                                                         \
    do {                                                                     \
        _Pragma("unroll")                                                    \
        for (int mt = 0; mt < 2; ++mt)                                       \
            _Pragma("unroll")                                                \
            for (int nt = 0; nt < 4; ++nt)                                   \
                acc[mt][nt] = __builtin_amdgcn_mfma_f32_16x16x32_bf16(       \
                                  A[mt], Bv[nt], acc[mt][nt], 0, 0, 0);      \
    } while (0)

// two-phase 8->4->1 reduce + bias + activation + store epilogue.
// C/D layout: col(b within 16-tile)=lane&15, row(i)=quad*4+q.
#define REDUCE_EPILOGUE(LASTF)                                               \
    do {                                                                     \
        if (wv >= 4) {                                                       \
            _Pragma("unroll")                                                \
            for (int mt = 0; mt < 2; ++mt)                                   \
                _Pragma("unroll")                                            \
                for (int nt = 0; nt < 4; ++nt)                               \
                    _Pragma("unroll")                                        \
                    for (int q2 = 0; q2 < 4; ++q2)                           \
                        s_red[wv - 4][nt * 16 + half][mt * 16 + quad * 4 + q2] = \
                            acc[mt][nt][q2];                                 \
        }                                                                    \
        __syncthreads();                                                     \
        if (wv < 4) {                                                        \
            _Pragma("unroll")                                                \
            for (int mt = 0; mt < 2; ++mt)                                   \
                _Pragma("unroll")                                            \
                for (int nt = 0; nt < 4; ++nt)                               \
                    _Pragma("unroll")                                        \
                    for (int q2 = 0; q2 < 4; ++q2)                           \
                        s_red[wv][nt * 16 + half][mt * 16 + quad * 4 + q2] += \
                            acc[mt][nt][q2];                                 \
        }                                                                    \
        __syncthreads();                                                     \
        const int b  = tid >> 3;                                             \
        const int i0 = (tid & 7) * 4;                                        \
        const float4 bv = *(const float4*)&bias[r * 32 + i0];                \
        float v[4] = {bv.x, bv.y, bv.z, bv.w};                               \
        _Pragma("unroll")                                                    \
        for (int w = 0; w < 4; ++w)                                          \
            _Pragma("unroll")                                                \
            for (int k = 0; k < 4; ++k)                                      \
                v[k] += s_red[w][b][i0 + k];                                 \
        if (LASTF) {                                                         \
            float4 o;                                                        \
            o.x = 1.0f / (1.0f + __expf(-v[0]));                             \
            o.y = 1.0f / (1.0f + __expf(-v[1]));                             \
            o.z = 1.0f / (1.0f + __expf(-v[2]));                             \
            o.w = 1.0f / (1.0f + __expf(-v[3]));                             \
            *(float4*)&out[(size_t)b * N_OUT_ +                              \
                           (r - (NB_ - N_OUT_ / 32)) * 32 + i0] = o;         \
        } else {                                                             \
            union { unsigned short s[4]; uint2 u; } o;                       \
            _Pragma("unroll")                                                \
            for (int k = 0; k < 4; ++k)                                      \
                o.s[k] = f2bf(1.0f / (1.0f + __expf(-v[k])));                \
            *(uint2*)&xout[((size_t)r * 64 + b) * 32 + i0] = o.u;            \
        }                                                                    \
    } while (0)

// ---------------- full step: depth-3 branchless pipeline --------------------
// One WG (8 waves) per row; wave wv takes the contiguous pair range
// [c0, c0+mv). Weights permuted -> block j at wbase + j*1024 shorts (pure
// stride). x-column offset for pair j held in lane j, fetched via readlane
// (lane index pinned scalar via readfirstlane -> single v_readlane_b32, no
// waterfall). Three rotating stages, clamped indices so the loop body is
// branchless and the scheduler keeps ~18 loads in flight per wave.

template <bool LAST>
__global__ __launch_bounds__(512, 4) void rowfull_k(
        const unsigned short* __restrict__ x,    // [NB][64][32] bf16 blocked
        unsigned short* __restrict__ xout,       // [NB][64][32] bf16 blocked
        float* __restrict__ out,                 // [B][N_OUT] f32 (LAST only)
        const unsigned short* __restrict__ wb,   // [NNZ][32][32] bf16, permuted
        const float* __restrict__ bias,
        const int2* __restrict__ pair2,          // row-sorted (n, c)
        const int* __restrict__ ptr,
        int row_base) {
    __shared__ float s_red[4][64][33];           // 33.8 KB

    const int r    = blockIdx.x + row_base;
    const int tid  = threadIdx.x;
    const int wv   = tid >> 6;                   // 0..7
    const int lane = tid & 63;
    const int half = lane & 15;
    const int quad = lane >> 4;

    const int beg = ptr[r], cnt = ptr[r + 1] - beg;
    // pin wave-uniform values to SGPRs (provable uniformity for readlane)
    const int c0 = __builtin_amdgcn_readfirstlane(beg + (cnt * wv) / 8);
    const int mv = __builtin_amdgcn_readfirstlane(beg + (cnt * (wv + 1)) / 8 - c0);

    // lane j holds x-offset (in shorts) of pair j of this wave's range
    int xoff = 0;
    if (lane < mv) xoff = pair2[c0 + lane].y * 2048;

    const int off16 = half * 32 + quad * 8;      // fragment offset in shorts
    const unsigned short* wbase = wb + (size_t)c0 * 1024 + off16;

    f32x4 acc[2][4] = {};
    bf16x8 A0[2], B0[4], A1[2], B1[4], A2[2], B2[4];

    // stage load, clamped: t > mv-1 re-reads pair mv-1 (harmless L1 hit)
    #define LDST(A, Bv, t)                                                   \
        do {                                                                 \
            int tt = ((t) < mv - 1) ? (t) : (mv - 1);                        \
            const unsigned short* wp = wbase + (size_t)tt * 1024;            \
            A[0] = ldfrag(wp);                                               \
            A[1] = ldfrag(wp + 512);                                         \
            int xo = __builtin_amdgcn_readlane(xoff, tt);                    \
            const unsigned short* xp = x + xo + off16;                       \
            Bv[0] = ldfrag(xp);                                              \
            Bv[1] = ldfrag(xp + 512);                                        \
            Bv[2] = ldfrag(xp + 1024);                                       \
            Bv[3] = ldfrag(xp + 1536);                                       \
        } while (0)

    if (mv > 0) {
        LDST(A0, B0, 0);
        LDST(A1, B1, 1);
        LDST(A2, B2, 2);
        int j = 0;
        while (j + 3 < mv) {
            MFMA8(A0, B0); LDST(A0, B0, j + 3);
            MFMA8(A1, B1); LDST(A1, B1, j + 4);
            MFMA8(A2, B2); LDST(A2, B2, j + 5);
            j += 3;
        }
        // remaining = mv - j in {1,2,3}
        MFMA8(A0, B0);
        if (mv - j > 1) MFMA8(A1, B1);
        if (mv - j > 2) MFMA8(A2, B2);
    }
    #undef LDST

    REDUCE_EPILOGUE(LAST);
}

// ---------------- step 0: column filter (c < 32), tiny work -----------------

__global__ __launch_bounds__(512, 4) void rowstep0_k(
        const unsigned short* __restrict__ x,
        unsigned short* __restrict__ xout,
        const unsigned short* __restrict__ wb,   // permuted order
        const float* __restrict__ bias,
        const int2* __restrict__ pair2,
        const int* __restrict__ ptr) {
    __shared__ int2  s_pairs[8][64];
    __shared__ float s_red[4][64][33];
    float* __restrict__ out = nullptr;           // unused (never LAST)

    const int r    = blockIdx.x;
    const int tid  = threadIdx.x;
    const int wv   = tid >> 6;
    const int lane = tid & 63;
    const int half = lane & 15;
    const int quad = lane >> 4;

    const int beg = ptr[r], cnt = ptr[r + 1] - beg;
    const int c0 = beg + (cnt * wv) / 8;
    const int m  = beg + (cnt * (wv + 1)) / 8 - c0;

    int2 pc = make_int2(0, 0);
    bool valid = (lane < m);
    if (valid) {
        int c = pair2[c0 + lane].y;
        pc = make_int2(c0 + lane, c);
        valid = (c < N_IN_ / 32);
    }
    unsigned long long mask = __ballot(valid);
    if (valid) {
        int pos = __popcll(mask & ((1ull << lane) - 1ull));
        s_pairs[wv][pos] = pc;                   // intra-wave only: no barrier
    }
    const int mv = __popcll(mask);

    const int off16 = half * 32 + quad * 8;

    f32x4 acc[2][4] = {};
    bf16x8 A0[2], B0[4], A1[2], B1[4];

    #define LDFRAGS0(A, Bv, p)                                               \
        do {                                                                 \
            const unsigned short* wp = wb + (size_t)(p).x * 1024 + off16;    \
            A[0] = ldfrag(wp);                                               \
            A[1] = ldfrag(wp + 512);                                         \
            const unsigned short* xp = x + (size_t)(p).y * 2048 + off16;     \
            Bv[0] = ldfrag(xp);                                              \
            Bv[1] = ldfrag(xp + 512);                                        \
            Bv[2] = ldfrag(xp + 1024);                                       \
            Bv[3] = ldfrag(xp + 1536);                                       \
        } while (0)

    if (mv > 0) { int2 p = s_pairs[wv][0]; LDFRAGS0(A0, B0, p); }
    int j = 0;
    while (j + 2 <= mv) {
        { int2 p = s_pairs[wv][j + 1]; LDFRAGS0(A1, B1, p); }
        MFMA8(A0, B0);
        if (j + 2 < mv) { int2 p = s_pairs[wv][j + 2]; LDFRAGS0(A0, B0, p); }
        MFMA8(A1, B1);
        j += 2;
    }
    if (j < mv) MFMA8(A0, B0);
    #undef LDFRAGS0

    REDUCE_EPILOGUE(false);
}

// ---------------- launcher --------------------------------------------------

extern "C" void kernel_launch(void* const* d_in, const int* in_sizes, int n_in,
                              void* d_out, int out_size, void* d_ws, size_t ws_size,
                              hipStream_t stream) {
    const float* inp    = (const float*)d_in[0];
    const float* blocks = (const float*)d_in[1];
    const float* bias   = (const float*)d_in[2];
    const int*   rows   = (const int*)d_in[3];
    const int*   cols   = (const int*)d_in[4];
    float*       out    = (float*)d_out;

    char* ws = (char*)d_ws;
    unsigned short* wbf = (unsigned short*)ws;                       // 53.69 MB
    unsigned short* x0  = (unsigned short*)(ws + 53686272u);         // 2 MB
    unsigned short* x1  = (unsigned short*)(ws + 53686272u + 2097152u);
    char*  idxbase      = ws + 53686272u + 2u * 2097152u;
    int*   rowptr = (int*)(idxbase);                                  // 513 ints
    int*   rowcnt = (int*)(idxbase + 4096);                           // 512 ints
    int2*  pair2  = (int2*)(idxbase + 8192);                          // NNZ int2

    // index build (must precede conv_w: permutation comes from pair2)
    zero_cnt<<<1, NB_, 0, stream>>>(rowcnt);
    hist<<<(NNZ_ + 255) / 256, 256, 0, stream>>>(rows, rowcnt);
    scan_k<<<1, NB_, 0, stream>>>(rowcnt, rowptr);
    scatter2<<<(NNZ_ + 255) / 256, 256, 0, stream>>>(rows, cols, rowptr, rowcnt, pair2);

    // weights -> bf16, permuted into row-sorted (pair) order
    conv_w<<<NNZ_, 256, 0, stream>>>(blocks, wbf, pair2);

    init_x<<<(B_ * H_) / 256, 256, 0, stream>>>(inp, x0);

    unsigned short* cur = x0;
    unsigned short* nxt = x1;
    // step 0: input nonzero only in first 32 col-blocks (filtered path)
    rowstep0_k<<<NB_, 512, 0, stream>>>(cur, nxt, wbf, bias, pair2, rowptr);
    { unsigned short* t = cur; cur = nxt; nxt = t; }
    // steps 1..6: full rows, deep-pipelined path
    for (int s = 1; s < 7; ++s) {
        rowfull_k<false><<<NB_, 512, 0, stream>>>(cur, nxt, nullptr, wbf, bias,
                                                  pair2, rowptr, 0);
        unsigned short* t = cur; cur = nxt; nxt = t;
    }
    // step 7: only rows 480..511 feed the output; fused sigmoid -> f32 out
    rowfull_k<true><<<N_OUT_ / 32, 512, 0, stream>>>(cur, nullptr, out, wbf, bias,
                                                     pair2, rowptr,
                                                     NB_ - N_OUT_ / 32);
}